// Round 6
// baseline (89.875 us; speedup 1.0000x reference)
//
#include <hip/hip_runtime.h>
#include <hip/hip_bf16.h>

typedef __attribute__((ext_vector_type(4))) float f32x4;
typedef __attribute__((ext_vector_type(2))) unsigned int u32x2;
typedef __attribute__((ext_vector_type(4))) unsigned int u32x4;
typedef __attribute__((ext_vector_type(8))) short bf16x8;

#define EPSF 1e-7f

// radial factor of logmap0(projx(expmap0(v*s, c), c), c)/s  applied to v, given sumsq(v)
__device__ __forceinline__ float radial_factor(float sumsq, float c, float s){
  float sc = sqrtf(c);
  float nv = sqrtf(sumsq);
  float nu = fmaxf(s*nv, EPSF);            // norm used in expmap0 (of v*s)
  float th = tanhf(sc*nu);
  float r1 = th/sc;                        // radius after expmap0
  float maxn = (1.0f - 1e-5f)/sc;
  float r2 = fminf(r1, maxn);              // radius after projx
  float n1 = fmaxf(r2, EPSF);              // norm recomputed in logmap0
  float a  = fminf(sc*n1, 1.0f - 1e-7f);
  float r3 = 0.5f*logf((1.0f + a)/(1.0f - a));   // artanh(a)
  return r3*r2/(sc*n1*nu);
}

__device__ __forceinline__ float gelu_f(float x){
  return 0.5f*x*(1.0f + erff(x*0.70710678118654752f));
}

__device__ __forceinline__ unsigned f2bf1(float f){   // RNE f32->bf16 (low 16 bits)
  unsigned u = __float_as_uint(f);
  return (u + 0x7FFFu + ((u>>16)&1u)) >> 16;
}
__device__ __forceinline__ unsigned f2bf_pk(float lo, float hi){
  unsigned ul = f2bf1(lo);
  unsigned uh = __float_as_uint(hi);
  uh = (uh + 0x7FFFu + ((uh>>16)&1u)) & 0xFFFF0000u;
  return ul | uh;
}

// ---------------- workspace layout (bytes) ----------------
#define WS_WC     0          // bf16 [64][800]
#define WS_BCOMB  204800     // f32 [64]
#define WS_W0AE   205056     // f32 [32][64]
#define WS_BROT0  213248     // f32 [5][64]
#define WS_BOWN0  214528     // f32 [5][64]
#define WS_W0AT   215808     // f32 [64][32]
#define WS_MB0    224000     // f32 [64]
#define WS_MB1    224256     // f32 [4]
#define WS_W1AE   224272     // f32 [16][4]

// ============ prep A: W_comb (blocks 0..49) + exp row-actions (blocks 50..59) ============
__global__ __launch_bounds__(256) void prep_a(
    const float* __restrict__ W_in, const float* __restrict__ b_in,
    const float* __restrict__ W_tan, const float* __restrict__ b_tan,
    const float* __restrict__ A_rot, const float* __restrict__ W0a,
    const float* __restrict__ bp0,
    unsigned short* __restrict__ Wc, float* __restrict__ bcomb,
    float* __restrict__ W0aE, float* __restrict__ brot0, float* __restrict__ bown0)
{
  __shared__ __align__(16) float Al[64][68];
  __shared__ __align__(16) float ST[64][68];   // ST[j][m] = S[m][j], S = A - A^T
  const int bid = blockIdx.x, t = threadIdx.x;

  if (bid < 50){
    if (bid == 0 && t < 64){
      float s = b_tan[t];
      for (int j = 0; j < 128; ++j) s += b_in[j]*W_tan[t*128+j];
      bcomb[t] = s;
    }
    const int g4 = bid*256 + t;              // 0..12799
    const int n = g4/200, k4 = (g4 - n*200)*4;
    f32x4 s = {0.f,0.f,0.f,0.f};
    if (k4 < 784){
      for (int j = 0; j < 128; ++j){
        float wt = W_tan[n*128+j];
        f32x4 wi = *(const f32x4*)(W_in + j*784 + k4);
        s += wt*wi;
      }
    }
    u32x2 st = { f2bf_pk(s[0], s[1]), f2bf_pk(s[2], s[3]) };
    *(u32x2*)(Wc + n*800 + k4) = st;
  } else {
    for (int m = t; m < 4096; m += 256){
      int r = m >> 6, c = m & 63;
      Al[r][c] = A_rot[m];
    }
    __syncthreads();
    for (int m = t; m < 4096; m += 256){
      int r = m >> 6, c = m & 63;
      ST[r][c] = Al[c][r] - Al[r][c];
    }
    __syncthreads();
    const int wv = t >> 6, lane = t & 63;
    const int row = (bid - 50)*4 + wv;      // 0..39, active < 37
    if (row < 37){
      float v, sgn;
      if (row < 32){ v = W0a[row*64 + lane]; sgn = 1.f; }
      else {
        const int r = row - 32;
        float b = bp0[r*64 + lane];
        float ssq = b*b;
        #pragma unroll
        for (int d = 1; d < 64; d <<= 1) ssq += __shfl_xor(ssq, d);
        float fc = radial_factor(ssq, 1.0f, 1.0f);
        v = b*fc;
        bown0[r*64 + lane] = v;
        sgn = -1.f;
      }
      float acc = v;
      for (int k = 1; k <= 12; ++k){
        const float coef = sgn/(float)k;
        float nv = 0.f;
        #pragma unroll
        for (int m = 0; m < 64; m += 4){
          f32x4 s4 = *(const f32x4*)&ST[lane][m];
          nv += __int_as_float(__builtin_amdgcn_readlane(__float_as_int(v), m+0))*s4[0];
          nv += __int_as_float(__builtin_amdgcn_readlane(__float_as_int(v), m+1))*s4[1];
          nv += __int_as_float(__builtin_amdgcn_readlane(__float_as_int(v), m+2))*s4[2];
          nv += __int_as_float(__builtin_amdgcn_readlane(__float_as_int(v), m+3))*s4[3];
        }
        nv *= coef;
        v = nv; acc += nv;
      }
      if (row < 32) W0aE[row*64 + lane] = acc;
      else          brot0[(row-32)*64 + lane] = acc;
    }
  }
}

// ============ prep B: small folds (1 block x 256) ============
__global__ __launch_bounds__(256) void prep_small(
    const float* __restrict__ bp1,
    const float* __restrict__ p_quat, const float* __restrict__ q_quat,
    const float* __restrict__ b0a, const float* __restrict__ W0b, const float* __restrict__ b0b,
    const float* __restrict__ W1a,
    const float* __restrict__ W0aE, const float* __restrict__ brot0, const float* __restrict__ bown0,
    float* __restrict__ W0aT, float* __restrict__ mb0, float* __restrict__ mb1,
    float* __restrict__ W1aE)
{
  __shared__ float g[5][32];
  __shared__ float c1[5][4];
  __shared__ float fac1[3];
  __shared__ float Mq[4][4];
  const int t = threadIdx.x;

  for (int i = t; i < 2048; i += 256){
    int o = i >> 6, k = i & 63;
    W0aT[k*32 + o] = W0aE[i];
  }
  if (t < 64){
    float s = 0.f;
    for (int r = 0; r < 5; ++r) s += bown0[r*64 + t];
    mb0[t] = s * 0.2f;
  }
  if (t < 160){
    int r = t >> 5, o = t & 31;
    float s = b0a[o];
    for (int k = 0; k < 64; ++k) s += brot0[r*64+k]*W0aE[o*64+k];
    g[r][o] = gelu_f(s);
  }
  if (t >= 192 && t < 195){
    int r = t - 192;
    float ssq = 0.f;
    for (int j = 0; j < 4; ++j){ float b = bp1[r*4+j]; ssq += b*b; }
    fac1[r] = radial_factor(ssq, 0.8f, 1.0f);
  }
  if (t == 224){
    float pw=p_quat[0],px=p_quat[1],py=p_quat[2],pz=p_quat[3];
    float n1 = sqrtf(pw*pw+px*px+py*py+pz*pz) + EPSF;
    pw/=n1; px/=n1; py/=n1; pz/=n1;
    float qw=q_quat[0],qx=q_quat[1],qy=q_quat[2],qz=q_quat[3];
    float n2 = sqrtf(qw*qw+qx*qx+qy*qy+qz*qz) + EPSF;
    qw/=n2; qx/=n2; qy/=n2; qz/=n2;
    float Lp[4][4] = {{pw,-px,-py,-pz},{px,pw,-pz,py},{py,pz,pw,-px},{pz,-py,px,pw}};
    float Rq[4][4] = {{qw,-qx,-qy,-qz},{qx,qw,qz,-qy},{qy,-qz,qw,qx},{qz,qy,-qx,qw}};
    #pragma unroll
    for (int i = 0; i < 4; ++i)
      #pragma unroll
      for (int k = 0; k < 4; ++k){
        float s = 0.f;
        #pragma unroll
        for (int m = 0; m < 4; ++m) s += Rq[i][m]*Lp[m][k];
        Mq[i][k] = s;
      }
  }
  __syncthreads();
  if (t < 20){
    int r = t >> 2, o = t & 3;
    float s = b0b[o];
    for (int k = 0; k < 32; ++k) s += g[r][k]*W0b[o*32+k];
    c1[r][o] = s;
  }
  __syncthreads();
  if (t < 4){
    float s = 0.f;
    for (int r = 0; r < 3; ++r) s += bp1[r*4+t]*fac1[r];
    for (int r = 0; r < 5; ++r) s += c1[r][t];
    mb1[t] = s * 0.125f;
  }
  if (t >= 64 && t < 128){
    int i = t - 64, o = i >> 2, kq = i & 3;
    float s = 0.f;
    #pragma unroll
    for (int j = 0; j < 4; ++j) s += W1a[o*4+j]*Mq[j][kq];
    W1aE[o*4+kq] = s;
  }
}

// ============ fused main: LDS-staged double-buffered GEMM -> row phase ============
// smem carve (bytes):
//   0     vlds   f32 [64][76]                 19456
//   19456 cWout  f32 [10][100]                 4000
//   23456 cmb0   f32 [64]                       256
//   23712 cW0b   f32 [4][32]                    512
//   24224 cW1aE  f32 [16][4]                    256
//   24480 cb0a[32] 24608 cb0b[4] 24624 cmb1[4] 24640 cb1a[16] 24704 cb1b[32] 24832 cbout[12]
//   24896 UNION (24576):
//     GEMM:  xs bf16 [2][64][40] 10240 | ws bf16 [2][64][40] 10240
//     row:   gv f32 [64][36] 9216 @24896 | g1 f32 [64][20] 5120 @34112
//            cW0aT f32 [64][32] 8192 @39232 | cW1b f32 [32][16] 2048 @47424
__global__ __launch_bounds__(256, 3) void main_fused(
    const float* __restrict__ x,
    const unsigned short* __restrict__ Wc,
    const float* __restrict__ bcomb,
    const float* __restrict__ W0aT,
    const float* __restrict__ mb0g, const float* __restrict__ mb1g,
    const float* __restrict__ W1aEg,
    const float* __restrict__ b0a, const float* __restrict__ W0b, const float* __restrict__ b0b,
    const float* __restrict__ b1a, const float* __restrict__ W1b, const float* __restrict__ b1b,
    const float* __restrict__ Wout, const float* __restrict__ bout,
    float* __restrict__ out)
{
  __shared__ __align__(16) char smem[49472];
  float* vlds   = (float*)smem;                    // stride 76
  float* cWoutS = (float*)(smem + 19456);
  float* cmb0S  = (float*)(smem + 23456);
  float* cW0bS  = (float*)(smem + 23712);
  float* cW1aES = (float*)(smem + 24224);
  float* cb0aS  = (float*)(smem + 24480);
  float* cb0bS  = (float*)(smem + 24608);
  float* cmb1S  = (float*)(smem + 24624);
  float* cb1aS  = (float*)(smem + 24640);
  float* cb1bS  = (float*)(smem + 24704);
  float* cboutS = (float*)(smem + 24832);
  unsigned short* xs  = (unsigned short*)(smem + 24896);          // [2][2560]
  unsigned short* wsb = (unsigned short*)(smem + 24896 + 10240);  // [2][2560]
  float* gv     = (float*)(smem + 24896);          // stride 36
  float* g1     = (float*)(smem + 34112);          // stride 20
  float* cW0aTS = (float*)(smem + 39232);          // [64][32]
  float* cW1bS  = (float*)(smem + 47424);          // [32][16]

  const int tid = threadIdx.x;
  const size_t rowBase = (size_t)blockIdx.x * 64;

  // ---- stage persistent small constants (outside union) ----
  if (tid < 64)  cmb0S[tid] = mb0g[tid];
  if (tid < 32)  cb0aS[tid] = b0a[tid];
  if (tid < 128) cW0bS[tid] = W0b[tid];
  if (tid < 4)   { cb0bS[tid] = b0b[tid]; cmb1S[tid] = mb1g[tid]; }
  if (tid < 64)  cW1aES[tid] = W1aEg[tid];
  if (tid < 16)  cb1aS[tid] = b1a[tid];
  if (tid < 32)  cb1bS[tid] = b1b[tid];
  if (tid < 10)  cboutS[tid] = bout[tid];
  for (int i = tid; i < 1000; i += 256) cWoutS[i] = Wout[i];

  // ---- GEMM setup ----
  const int lane = tid & 63;
  const int w    = tid >> 6;
  const int wr   = w >> 1, wc = w & 1;
  const int lr   = lane & 15, lkg = lane >> 4;

  // staging descriptors: 12 chunks of 1KB, wave w owns chunks 3w..3w+2
  const char* gpd[3]; int lod[3]; int advd[3]; int thrd[3]; int isxd[3];
  #pragma unroll
  for (int d = 0; d < 3; ++d){
    const int c = w*3 + d;
    if (c < 8){                       // x chunk: 8 rows x 32 f32
      const int row = c*8 + (lane >> 3), seg = lane & 7;
      gpd[d]  = (const char*)(x + (rowBase + (size_t)row)*784 + seg*4);
      lod[d]  = row*40 + seg*4;       // bf16 index
      advd[d] = 128;                  // 32 f32
      thrd[d] = 784 - seg*4;
      isxd[d] = 1;
    } else {                          // Wc chunk: 16 rows x 32 bf16
      const int row = (c - 8)*16 + (lane >> 2), seg = lane & 3;
      gpd[d]  = (const char*)(Wc + (size_t)row*800 + seg*8);
      lod[d]  = row*40 + seg*8;       // bf16 index
      advd[d] = 64;                   // 32 bf16
      thrd[d] = 1 << 30;
      isxd[d] = 0;
    }
  }
  // LDS read offsets (bf16 index)
  const int aof0 = (wr*32 + lr)*40 + lkg*8;
  const int aof1 = aof0 + 16*40;
  const int bof0 = (wc*32 + lr)*40 + lkg*8;
  const int bof1 = bof0 + 16*40;

  // ---- prologue: stage slab 0 ----
  #pragma unroll
  for (int d = 0; d < 3; ++d){
    u32x4 v = *(const u32x4*)gpd[d];
    gpd[d] += advd[d];
    if (isxd[d]){
      f32x4 f = __builtin_bit_cast(f32x4, v);
      u32x2 p = { f2bf_pk(f[0], f[1]), f2bf_pk(f[2], f[3]) };
      *(u32x2*)(xs + lod[d]) = p;
    } else {
      *(u32x4*)(wsb + lod[d]) = v;
    }
  }
  __syncthreads();

  // ---- main K loop: 25 iters of K=32, double-buffered ----
  f32x4 acc00 = {}, acc01 = {}, acc10 = {}, acc11 = {};
  for (int t = 0; t < 25; ++t){
    const int cur = t & 1;
    const bool have = (t < 24);
    u32x4 sv0 = {0,0,0,0}, sv1 = {0,0,0,0}, sv2 = {0,0,0,0};
    if (have){
      const int k0n = (t + 1)*32;
      if (k0n < thrd[0]) sv0 = *(const u32x4*)gpd[0];
      if (k0n < thrd[1]) sv1 = *(const u32x4*)gpd[1];
      if (k0n < thrd[2]) sv2 = *(const u32x4*)gpd[2];
      gpd[0] += advd[0]; gpd[1] += advd[1]; gpd[2] += advd[2];
    }
    const unsigned short* xc = xs  + cur*2560;
    const unsigned short* wcb = wsb + cur*2560;
    bf16x8 a0 = *(const bf16x8*)(xc  + aof0);
    bf16x8 a1 = *(const bf16x8*)(xc  + aof1);
    bf16x8 b0 = *(const bf16x8*)(wcb + bof0);
    bf16x8 b1 = *(const bf16x8*)(wcb + bof1);
    acc00 = __builtin_amdgcn_mfma_f32_16x16x32_bf16(a0, b0, acc00, 0, 0, 0);
    acc01 = __builtin_amdgcn_mfma_f32_16x16x32_bf16(a0, b1, acc01, 0, 0, 0);
    acc10 = __builtin_amdgcn_mfma_f32_16x16x32_bf16(a1, b0, acc10, 0, 0, 0);
    acc11 = __builtin_amdgcn_mfma_f32_16x16x32_bf16(a1, b1, acc11, 0, 0, 0);
    if (have){
      unsigned short* xn = xs  + (cur ^ 1)*2560;
      unsigned short* wn = wsb + (cur ^ 1)*2560;
      if (isxd[0]){ f32x4 f = __builtin_bit_cast(f32x4, sv0);
        u32x2 p = { f2bf_pk(f[0], f[1]), f2bf_pk(f[2], f[3]) }; *(u32x2*)(xn + lod[0]) = p; }
      else { *(u32x4*)(wn + lod[0]) = sv0; }
      if (isxd[1]){ f32x4 f = __builtin_bit_cast(f32x4, sv1);
        u32x2 p = { f2bf_pk(f[0], f[1]), f2bf_pk(f[2], f[3]) }; *(u32x2*)(xn + lod[1]) = p; }
      else { *(u32x4*)(wn + lod[1]) = sv1; }
      if (isxd[2]){ f32x4 f = __builtin_bit_cast(f32x4, sv2);
        u32x2 p = { f2bf_pk(f[0], f[1]), f2bf_pk(f[2], f[3]) }; *(u32x2*)(xn + lod[2]) = p; }
      else { *(u32x4*)(wn + lod[2]) = sv2; }
    }
    __syncthreads();
  }

  // ---- epilogue: acc -> vlds (with bias) ----
  {
    f32x4 accA[2][2] = { {acc00, acc01}, {acc10, acc11} };
    #pragma unroll
    for (int fi = 0; fi < 2; ++fi){
      #pragma unroll
      for (int fj = 0; fj < 2; ++fj){
        const int col = wc*32 + fj*16 + lr;
        const int r0  = wr*32 + fi*16 + lkg*4;
        const float bc = bcomb[col];
        #pragma unroll
        for (int j = 0; j < 4; ++j)
          vlds[(r0 + j)*76 + col] = accA[fi][fj][j] + bc;
      }
    }
  }
  // ---- stage row-phase weights into union region (GEMM slabs dead now) ----
  for (int i = tid; i < 2048; i += 256) cW0aTS[i] = W0aT[i];
  for (int i = tid; i < 512;  i += 256) cW1bS[i]  = W1b[i];
  __syncthreads();

  const int row = tid >> 2, p4 = tid & 3;

  // R1: v_tan0 = radial(v)  (in place)
  {
    f32x4 rv[4];
    float* vptr = &vlds[row*76 + p4*16];
    #pragma unroll
    for (int i = 0; i < 4; ++i) rv[i] = ((const f32x4*)vptr)[i];
    float ssq = 0.f;
    #pragma unroll
    for (int i = 0; i < 4; ++i)
      ssq += rv[i][0]*rv[i][0] + rv[i][1]*rv[i][1] + rv[i][2]*rv[i][2] + rv[i][3]*rv[i][3];
    ssq += __shfl_xor(ssq, 1); ssq += __shfl_xor(ssq, 2);
    const float fac = radial_factor(ssq, 1.0f, 1.0f);
    #pragma unroll
    for (int i = 0; i < 4; ++i){ rv[i] *= fac; ((f32x4*)vptr)[i] = rv[i]; }
  }
  __syncthreads();

  // R2: a0 = W0aE @ (2*vt0 - mb0) + b0a ; g0 = gelu(a0)   (8 outputs/thread)
  {
    const int og = p4;
    float a0o[8];
    #pragma unroll
    for (int j = 0; j < 8; ++j) a0o[j] = cb0aS[og*8 + j];
    #pragma unroll 4
    for (int k = 0; k < 64; k += 4){
      f32x4 vtv = *(const f32x4*)&vlds[row*76 + k];
      f32x4 mm  = *(const f32x4*)&cmb0S[k];
      #pragma unroll
      for (int u = 0; u < 4; ++u){
        const float vc = 2.f*vtv[u] - mm[u];
        const f32x4* wp = (const f32x4*)&cW0aTS[(k+u)*32 + og*8];
        f32x4 w0 = wp[0], w1 = wp[1];
        #pragma unroll
        for (int j = 0; j < 4; ++j){ a0o[j] += w0[j]*vc; a0o[4+j] += w1[j]*vc; }
      }
    }
    #pragma unroll
    for (int j = 0; j < 8; ++j) gv[row*36 + og*8 + j] = gelu_f(a0o[j]);
  }
  __syncthreads();

  // R3: v1 = W0b@g0 + b0b (1 comp/thread); v_tan1, v_comb1
  {
    const int o1 = p4;
    float a1 = cb0bS[o1];
    #pragma unroll
    for (int k = 0; k < 32; k += 4){
      f32x4 gg = *(const f32x4*)&gv[row*36 + k];
      f32x4 ww = *(const f32x4*)&cW0bS[o1*32 + k];
      a1 += gg[0]*ww[0] + gg[1]*ww[1] + gg[2]*ww[2] + gg[3]*ww[3];
    }
    float ss1 = a1*a1;
    ss1 += __shfl_xor(ss1, 1); ss1 += __shfl_xor(ss1, 2);
    const float f1v = radial_factor(ss1, 0.8f, 0.8f);
    const float vt1 = a1*f1v;
    vlds[row*76 + 64 + o1] = vt1;
    vlds[row*76 + 68 + o1] = 2.f*vt1 - cmb1S[o1];
  }
  __syncthreads();

  // R4: a1 = W1aE @ vc1 + b1a ; g1 = gelu  (4 outputs/thread)
  {
    const f32x4 vc1 = *(const f32x4*)&vlds[row*76 + 68];
    #pragma unroll
    for (int j = 0; j < 4; ++j){
      const int o = p4*4 + j;
      float s1 = cb1aS[o] + cW1aES[o*4+0]*vc1[0] + cW1aES[o*4+1]*vc1[1]
                          + cW1aES[o*4+2]*vc1[2] + cW1aES[o*4+3]*vc1[3];
      g1[row*20 + o] = gelu_f(s1);
    }
  }
  __syncthreads();

  // R5: v2 = W1b@g1 + b1b (8/thread); v_tan2 -> gv
  {
    float v2[8]; float ss2 = 0.f;
    #pragma unroll
    for (int j = 0; j < 8; ++j){
      const int o = p4*8 + j;
      float s = cb1bS[o];
      #pragma unroll
      for (int k = 0; k < 16; k += 4){
        f32x4 gg = *(const f32x4*)&g1[row*20 + k];
        f32x4 ww = *(const f32x4*)&cW1bS[o*16 + k];
        s += gg[0]*ww[0] + gg[1]*ww[1] + gg[2]*ww[2] + gg[3]*ww[3];
      }
      v2[j] = s; ss2 += s*s;
    }
    ss2 += __shfl_xor(ss2, 1); ss2 += __shfl_xor(ss2, 2);
    const float f2v = radial_factor(ss2, 1.2f, 0.6f);
    #pragma unroll
    for (int j = 0; j < 8; ++j) gv[row*36 + p4*8 + j] = v2[j]*f2v;
  }
  __syncthreads();

  // R6: out = W_out @ concat(vt0, vt1, vt2) + b_out
  for (int idx = tid; idx < 640; idx += 256){
    const int r6 = idx/10, o = idx - r6*10;
    float s = cboutS[o];
    const float* wrow = &cWoutS[o*100];
    const float* vrow = &vlds[r6*76];
    #pragma unroll 4
    for (int k = 0; k < 68; k += 4){
      f32x4 a = *(const f32x4*)(vrow + k);
      f32x4 b = *(const f32x4*)(wrow + k);
      s += a[0]*b[0] + a[1]*b[1] + a[2]*b[2] + a[3]*b[3];
    }
    const float* v2row = &gv[r6*36];
    #pragma unroll 4
    for (int k = 0; k < 32; k += 4){
      f32x4 a = *(const f32x4*)(v2row + k);
      f32x4 b = *(const f32x4*)(wrow + 68 + k);
      s += a[0]*b[0] + a[1]*b[1] + a[2]*b[2] + a[3]*b[3];
    }
    out[(rowBase + (size_t)r6)*10 + o] = s;
  }
}

extern "C" void kernel_launch(void* const* d_in, const int* in_sizes, int n_in,
                              void* d_out, int out_size, void* d_ws, size_t ws_size,
                              hipStream_t stream)
{
  (void)n_in; (void)out_size; (void)ws_size;
  const float* x      = (const float*)d_in[0];
  const float* W_in   = (const float*)d_in[1];
  const float* b_in   = (const float*)d_in[2];
  const float* W_tan  = (const float*)d_in[3];
  const float* b_tan  = (const float*)d_in[4];
  const float* bp0    = (const float*)d_in[5];
  const float* bp1    = (const float*)d_in[6];
  /* bp2 = d_in[7] — dead in reference */
  const float* A_rot  = (const float*)d_in[8];
  const float* p_quat = (const float*)d_in[9];
  const float* q_quat = (const float*)d_in[10];
  const float* W0a    = (const float*)d_in[11];
  const float* b0a    = (const float*)d_in[12];
  const float* W0b    = (const float*)d_in[13];
  const float* b0b    = (const float*)d_in[14];
  const float* W1a    = (const float*)d_in[15];
  const float* b1a    = (const float*)d_in[16];
  const float* W1b    = (const float*)d_in[17];
  const float* b1b    = (const float*)d_in[18];
  const float* W_out  = (const float*)d_in[19];
  const float* b_out  = (const float*)d_in[20];

  char* ws = (char*)d_ws;
  unsigned short* Wc = (unsigned short*)(ws + WS_WC);
  float* bcomb = (float*)(ws + WS_BCOMB);
  float* W0aE  = (float*)(ws + WS_W0AE);
  float* brot0 = (float*)(ws + WS_BROT0);
  float* bown0 = (float*)(ws + WS_BOWN0);
  float* W0aT  = (float*)(ws + WS_W0AT);
  float* mb0   = (float*)(ws + WS_MB0);
  float* mb1   = (float*)(ws + WS_MB1);
  float* W1aE  = (float*)(ws + WS_W1AE);

  const int Brows = in_sizes[0] / 784;
  const int nblk  = Brows / 64;

  prep_a<<<60, 256, 0, stream>>>(W_in, b_in, W_tan, b_tan, A_rot, W0a, bp0,
                                 Wc, bcomb, W0aE, brot0, bown0);
  prep_small<<<1, 256, 0, stream>>>(bp1, p_quat, q_quat, b0a, W0b, b0b, W1a,
                                    W0aE, brot0, bown0, W0aT, mb0, mb1, W1aE);
  main_fused<<<nblk, 256, 0, stream>>>(x, Wc, bcomb, W0aT, mb0, mb1, W1aE,
                                       b0a, W0b, b0b, b1a, W1b, b1b,
                                       W_out, b_out, (float*)d_out);
}

// Round 7
// 85.636 us; speedup vs baseline: 1.0495x; 1.0495x over previous
//
#include <hip/hip_runtime.h>
#include <hip/hip_bf16.h>

typedef __attribute__((ext_vector_type(4))) float f32x4;
typedef __attribute__((ext_vector_type(2))) unsigned int u32x2;
typedef __attribute__((ext_vector_type(4))) unsigned int u32x4;
typedef __attribute__((ext_vector_type(8))) short bf16x8;

#define EPSF 1e-7f

__device__ __forceinline__ float radial_factor(float sumsq, float c, float s){
  float sc = sqrtf(c);
  float nv = sqrtf(sumsq);
  float nu = fmaxf(s*nv, EPSF);
  float th = tanhf(sc*nu);
  float r1 = th/sc;
  float maxn = (1.0f - 1e-5f)/sc;
  float r2 = fminf(r1, maxn);
  float n1 = fmaxf(r2, EPSF);
  float a  = fminf(sc*n1, 1.0f - 1e-7f);
  float r3 = 0.5f*logf((1.0f + a)/(1.0f - a));
  return r3*r2/(sc*n1*nu);
}

__device__ __forceinline__ float gelu_f(float x){
  return 0.5f*x*(1.0f + erff(x*0.70710678118654752f));
}

__device__ __forceinline__ unsigned f2bf1(float f){
  unsigned u = __float_as_uint(f);
  return (u + 0x7FFFu + ((u>>16)&1u)) >> 16;
}
__device__ __forceinline__ unsigned f2bf_pk(float lo, float hi){
  unsigned ul = f2bf1(lo);
  unsigned uh = __float_as_uint(hi);
  uh = (uh + 0x7FFFu + ((uh>>16)&1u)) & 0xFFFF0000u;
  return ul | uh;
}

// async global->LDS, 16B per lane; LDS dest must be wave-uniform base (linear fill)
__device__ __forceinline__ void gload_lds16(const void* g, void* l){
  __builtin_amdgcn_global_load_lds((const __attribute__((address_space(1))) unsigned int*)g,
                                   (__attribute__((address_space(3))) unsigned int*)l,
                                   16, 0, 0);
}

// ---------------- workspace layout (bytes) ----------------
// Wc_s: bf16, swizzled slab layout [25 slabs][64 rows][4 slots of 8 bf16]
//       slot for logical quad q of row n = q ^ ((n>>1)&3)
#define WS_WC     0          // bf16 25*2048 = 51200 elts = 102400 B
#define WS_BCOMB  204800     // f32 [64]
#define WS_W0AE   205056     // f32 [32][64]
#define WS_BROT0  213248     // f32 [5][64]
#define WS_BOWN0  214528     // f32 [5][64]
#define WS_W0AT   215808     // f32 [64][32]
#define WS_MB0    224000     // f32 [64]
#define WS_MB1    224256     // f32 [4]
#define WS_W1AE   224272     // f32 [16][4]
#define WS_ZERO   224528     // f32 [16] zeros

// ============ prep A: W_comb (blocks 0..49, swizzled store) + exp row-actions ============
__global__ __launch_bounds__(256) void prep_a(
    const float* __restrict__ W_in, const float* __restrict__ b_in,
    const float* __restrict__ W_tan, const float* __restrict__ b_tan,
    const float* __restrict__ A_rot, const float* __restrict__ W0a,
    const float* __restrict__ bp0,
    unsigned short* __restrict__ Wc, float* __restrict__ bcomb,
    float* __restrict__ W0aE, float* __restrict__ brot0, float* __restrict__ bown0)
{
  __shared__ __align__(16) float Al[64][68];
  __shared__ __align__(16) float ST[64][68];
  const int bid = blockIdx.x, t = threadIdx.x;

  if (bid < 50){
    if (bid == 0 && t < 64){
      float s = b_tan[t];
      for (int j = 0; j < 128; ++j) s += b_in[j]*W_tan[t*128+j];
      bcomb[t] = s;
    }
    const int g4 = bid*256 + t;              // 0..12799
    const int n = g4/200, k4 = (g4 - n*200)*4;   // k4 in [0,800)
    f32x4 s = {0.f,0.f,0.f,0.f};
    if (k4 < 784){
      for (int j = 0; j < 128; ++j){
        float wt = W_tan[n*128+j];
        f32x4 wi = *(const f32x4*)(W_in + j*784 + k4);
        s += wt*wi;
      }
    }
    u32x2 st = { f2bf_pk(s[0], s[1]), f2bf_pk(s[2], s[3]) };
    // swizzled slab store
    const int tsl = k4 >> 5;
    const int q   = (k4 >> 3) & 3;
    const int qp  = q ^ ((n >> 1) & 3);
    const int idx = tsl*2048 + n*32 + qp*8 + (k4 & 7);
    *(u32x2*)(Wc + idx) = st;
  } else {
    for (int m = t; m < 4096; m += 256){
      int r = m >> 6, c = m & 63;
      Al[r][c] = A_rot[m];
    }
    __syncthreads();
    for (int m = t; m < 4096; m += 256){
      int r = m >> 6, c = m & 63;
      ST[r][c] = Al[c][r] - Al[r][c];
    }
    __syncthreads();
    const int wv = t >> 6, lane = t & 63;
    const int row = (bid - 50)*4 + wv;
    if (row < 37){
      float v, sgn;
      if (row < 32){ v = W0a[row*64 + lane]; sgn = 1.f; }
      else {
        const int r = row - 32;
        float b = bp0[r*64 + lane];
        float ssq = b*b;
        #pragma unroll
        for (int d = 1; d < 64; d <<= 1) ssq += __shfl_xor(ssq, d);
        float fc = radial_factor(ssq, 1.0f, 1.0f);
        v = b*fc;
        bown0[r*64 + lane] = v;
        sgn = -1.f;
      }
      float acc = v;
      for (int k = 1; k <= 12; ++k){
        const float coef = sgn/(float)k;
        float nv = 0.f;
        #pragma unroll
        for (int m = 0; m < 64; m += 4){
          f32x4 s4 = *(const f32x4*)&ST[lane][m];
          nv += __int_as_float(__builtin_amdgcn_readlane(__float_as_int(v), m+0))*s4[0];
          nv += __int_as_float(__builtin_amdgcn_readlane(__float_as_int(v), m+1))*s4[1];
          nv += __int_as_float(__builtin_amdgcn_readlane(__float_as_int(v), m+2))*s4[2];
          nv += __int_as_float(__builtin_amdgcn_readlane(__float_as_int(v), m+3))*s4[3];
        }
        nv *= coef;
        v = nv; acc += nv;
      }
      if (row < 32) W0aE[row*64 + lane] = acc;
      else          brot0[(row-32)*64 + lane] = acc;
    }
  }
}

// ============ prep B: small folds (1 block x 256) ============
__global__ __launch_bounds__(256) void prep_small(
    const float* __restrict__ bp1,
    const float* __restrict__ p_quat, const float* __restrict__ q_quat,
    const float* __restrict__ b0a, const float* __restrict__ W0b, const float* __restrict__ b0b,
    const float* __restrict__ W1a,
    const float* __restrict__ W0aE, const float* __restrict__ brot0, const float* __restrict__ bown0,
    float* __restrict__ W0aT, float* __restrict__ mb0, float* __restrict__ mb1,
    float* __restrict__ W1aE, float* __restrict__ zerog)
{
  __shared__ float g[5][32];
  __shared__ float c1[5][4];
  __shared__ float fac1[3];
  __shared__ float Mq[4][4];
  const int t = threadIdx.x;

  for (int i = t; i < 2048; i += 256){
    int o = i >> 6, k = i & 63;
    W0aT[k*32 + o] = W0aE[i];
  }
  if (t >= 240) zerog[t - 240] = 0.f;
  if (t < 64){
    float s = 0.f;
    for (int r = 0; r < 5; ++r) s += bown0[r*64 + t];
    mb0[t] = s * 0.2f;
  }
  if (t < 160){
    int r = t >> 5, o = t & 31;
    float s = b0a[o];
    for (int k = 0; k < 64; ++k) s += brot0[r*64+k]*W0aE[o*64+k];
    g[r][o] = gelu_f(s);
  }
  if (t >= 192 && t < 195){
    int r = t - 192;
    float ssq = 0.f;
    for (int j = 0; j < 4; ++j){ float b = bp1[r*4+j]; ssq += b*b; }
    fac1[r] = radial_factor(ssq, 0.8f, 1.0f);
  }
  if (t == 224){
    float pw=p_quat[0],px=p_quat[1],py=p_quat[2],pz=p_quat[3];
    float n1 = sqrtf(pw*pw+px*px+py*py+pz*pz) + EPSF;
    pw/=n1; px/=n1; py/=n1; pz/=n1;
    float qw=q_quat[0],qx=q_quat[1],qy=q_quat[2],qz=q_quat[3];
    float n2 = sqrtf(qw*qw+qx*qx+qy*qy+qz*qz) + EPSF;
    qw/=n2; qx/=n2; qy/=n2; qz/=n2;
    float Lp[4][4] = {{pw,-px,-py,-pz},{px,pw,-pz,py},{py,pz,pw,-px},{pz,-py,px,pw}};
    float Rq[4][4] = {{qw,-qx,-qy,-qz},{qx,qw,qz,-qy},{qy,-qz,qw,qx},{qz,qy,-qx,qw}};
    #pragma unroll
    for (int i = 0; i < 4; ++i)
      #pragma unroll
      for (int k = 0; k < 4; ++k){
        float s = 0.f;
        #pragma unroll
        for (int m = 0; m < 4; ++m) s += Rq[i][m]*Lp[m][k];
        Mq[i][k] = s;
      }
  }
  __syncthreads();
  if (t < 20){
    int r = t >> 2, o = t & 3;
    float s = b0b[o];
    for (int k = 0; k < 32; ++k) s += g[r][k]*W0b[o*32+k];
    c1[r][o] = s;
  }
  __syncthreads();
  if (t < 4){
    float s = 0.f;
    for (int r = 0; r < 3; ++r) s += bp1[r*4+t]*fac1[r];
    for (int r = 0; r < 5; ++r) s += c1[r][t];
    mb1[t] = s * 0.125f;
  }
  if (t >= 64 && t < 128){
    int i = t - 64, o = i >> 2, kq = i & 3;
    float s = 0.f;
    #pragma unroll
    for (int j = 0; j < 4; ++j) s += W1a[o*4+j]*Mq[j][kq];
    W1aE[o*4+kq] = s;
  }
}

// ============ fused main: global_load_lds double-buffered GEMM -> row phase ============
// smem (bytes):
//   0     vlds  f32 [64][76]   19456
//   19456 cWout f32 [1000]      4000  -> 23456
//   23456 cbcomb[64]            256   -> 23712
//   23712 cmb0[64]              256   -> 23968
//   23968 cW0b[128]             512   -> 24480
//   24480 cW1aE[64]             256   -> 24736
//   24736 cb0a[32]              128   -> 24864
//   24864 cb0b[4]               16    -> 24880
//   24880 cmb1[4]               16    -> 24896
//   24896 cb1a[16]              64    -> 24960
//   24960 cb1b[32]              128   -> 25088
//   25088 cbout[12]+pad         64    -> 25152
//   25152 UNION 24576           -> 49728
//     GEMM: xs f32 [2][64][32]  (2x8192, swizzled quads) @25152
//           wcs bf16 [2][64][32](2x4096, swizzled quads) @41536
//     ROW:  gv [64][36] @25152 | g1 [64][20] @34368 | cW0aT [64][32] @39488 | cW1b [512] @47680
__global__ __launch_bounds__(256, 3) void main_fused(
    const float* __restrict__ x,
    const unsigned short* __restrict__ Wcs,
    const float* __restrict__ bcomb,
    const float* __restrict__ W0aT,
    const float* __restrict__ mb0g, const float* __restrict__ mb1g,
    const float* __restrict__ W1aEg,
    const float* __restrict__ b0a, const float* __restrict__ W0b, const float* __restrict__ b0b,
    const float* __restrict__ b1a, const float* __restrict__ W1b, const float* __restrict__ b1b,
    const float* __restrict__ Wout, const float* __restrict__ bout,
    const float* __restrict__ zerog,
    float* __restrict__ out)
{
  __shared__ __align__(16) char smem[49728];
  float* vlds   = (float*)smem;                    // stride 76
  float* cWoutS = (float*)(smem + 19456);
  float* cbcombS= (float*)(smem + 23456);
  float* cmb0S  = (float*)(smem + 23712);
  float* cW0bS  = (float*)(smem + 23968);
  float* cW1aES = (float*)(smem + 24480);
  float* cb0aS  = (float*)(smem + 24736);
  float* cb0bS  = (float*)(smem + 24864);
  float* cmb1S  = (float*)(smem + 24880);
  float* cb1aS  = (float*)(smem + 24896);
  float* cb1bS  = (float*)(smem + 24960);
  float* cboutS = (float*)(smem + 25088);
  char*  xsB    = smem + 25152;                    // [2][8192] f32 slabs
  char*  wcsB   = smem + 41536;                    // [2][4096] bf16 slabs
  float* gv     = (float*)(smem + 25152);          // stride 36
  float* g1     = (float*)(smem + 34368);          // stride 20
  float* cW0aTS = (float*)(smem + 39488);          // [64][32]
  float* cW1bS  = (float*)(smem + 47680);          // [32][16]

  const int tid = threadIdx.x;
  const size_t rowBase = (size_t)blockIdx.x * 64;

  // ---- stage persistent small constants ----
  if (tid < 64)  cbcombS[tid] = bcomb[tid];
  if (tid < 64)  cmb0S[tid] = mb0g[tid];
  if (tid < 32)  cb0aS[tid] = b0a[tid];
  if (tid < 128) cW0bS[tid] = W0b[tid];
  if (tid < 4)   { cb0bS[tid] = b0b[tid]; cmb1S[tid] = mb1g[tid]; }
  if (tid < 64)  cW1aES[tid] = W1aEg[tid];
  if (tid < 16)  cb1aS[tid] = b1a[tid];
  if (tid < 32)  cb1bS[tid] = b1b[tid];
  if (tid < 10)  cboutS[tid] = bout[tid];
  for (int i = tid; i < 1000; i += 256) cWoutS[i] = Wout[i];

  // ---- GEMM setup ----
  const int lane = tid & 63;
  const int w    = tid >> 6;
  const int wr   = w >> 1, wc = w & 1;
  const int lr   = lane & 15, lkg = lane >> 4;

  // staging source pointers (per lane)
  const int row8 = lane >> 3;                 // x-call: row within 8-row group
  const int qs   = lane & 7;                  // LDS quad slot
  const int qoff = qs ^ row8;                 // logical quad at this slot (x swizzle)
  const float* xsrcA = x + (rowBase + (size_t)(8*w     + row8))*784 + qoff*4;
  const float* xsrcB = x + (rowBase + (size_t)(8*(w+4) + row8))*784 + qoff*4;
  const unsigned short* wsrc = Wcs + (16*w + (lane>>2))*32 + (lane&3)*8;

  // LDS read byte-offsets (A: f32 rows of 128B; B: bf16 rows of 64B)
  const int rA0 = wr*32 + lr;
  const int sA0 = (2*lkg)     ^ (lr & 7);
  const int sA1 = (2*lkg + 1) ^ (lr & 7);
  const int offA00 = rA0*128 + sA0*16;
  const int offA01 = rA0*128 + sA1*16;
  const int rB0 = wc*32 + lr;
  const int sB  = lkg ^ ((rB0 >> 1) & 3);
  const int offB0 = rB0*64 + sB*16;

#define STAGE(slab, buf) do{                                                   \
    const int ks_ = (slab)*32;                                                 \
    char* xd_ = xsB  + (buf)*8192;                                             \
    char* wd_ = wcsB + (buf)*4096;                                             \
    const float* sa_ = (ks_ + qoff*4 < 784) ? (xsrcA + ks_) : zerog;           \
    const float* sb_ = (ks_ + qoff*4 < 784) ? (xsrcB + ks_) : zerog;           \
    gload_lds16(sa_, xd_ + w*1024);                                            \
    gload_lds16(sb_, xd_ + (w+4)*1024);                                        \
    gload_lds16(wsrc + (slab)*2048, wd_ + w*1024);                             \
  }while(0)

  // ---- prologue: stage slab 0 ----
  STAGE(0, 0);
  __syncthreads();

  // ---- main K loop: 25 slabs of K=32, double-buffered ----
  f32x4 acc00 = {}, acc01 = {}, acc10 = {}, acc11 = {};
  for (int t = 0; t < 25; ++t){
    const int cur = t & 1;
    if (t < 24) STAGE(t+1, cur^1);
    const char* xb = xsB  + cur*8192;
    const char* wb = wcsB + cur*4096;
    f32x4 a00 = *(const f32x4*)(xb + offA00);
    f32x4 a01 = *(const f32x4*)(xb + offA01);
    f32x4 a10 = *(const f32x4*)(xb + offA00 + 2048);
    f32x4 a11 = *(const f32x4*)(xb + offA01 + 2048);
    bf16x8 b0 = *(const bf16x8*)(wb + offB0);
    bf16x8 b1 = *(const bf16x8*)(wb + offB0 + 1024);
    u32x4 pk0 = { f2bf_pk(a00[0],a00[1]), f2bf_pk(a00[2],a00[3]),
                  f2bf_pk(a01[0],a01[1]), f2bf_pk(a01[2],a01[3]) };
    u32x4 pk1 = { f2bf_pk(a10[0],a10[1]), f2bf_pk(a10[2],a10[3]),
                  f2bf_pk(a11[0],a11[1]), f2bf_pk(a11[2],a11[3]) };
    bf16x8 af0 = __builtin_bit_cast(bf16x8, pk0);
    bf16x8 af1 = __builtin_bit_cast(bf16x8, pk1);
    acc00 = __builtin_amdgcn_mfma_f32_16x16x32_bf16(af0, b0, acc00, 0, 0, 0);
    acc01 = __builtin_amdgcn_mfma_f32_16x16x32_bf16(af0, b1, acc01, 0, 0, 0);
    acc10 = __builtin_amdgcn_mfma_f32_16x16x32_bf16(af1, b0, acc10, 0, 0, 0);
    acc11 = __builtin_amdgcn_mfma_f32_16x16x32_bf16(af1, b1, acc11, 0, 0, 0);
    __syncthreads();
  }
#undef STAGE

  // ---- epilogue: acc -> vlds (with bias); stage row-phase weights into union ----
  {
    f32x4 accA[2][2] = { {acc00, acc01}, {acc10, acc11} };
    #pragma unroll
    for (int fi = 0; fi < 2; ++fi){
      #pragma unroll
      for (int fj = 0; fj < 2; ++fj){
        const int col = wc*32 + fj*16 + lr;
        const int r0  = wr*32 + fi*16 + lkg*4;
        const float bc = cbcombS[col];
        #pragma unroll
        for (int j = 0; j < 4; ++j)
          vlds[(r0 + j)*76 + col] = accA[fi][fj][j] + bc;
      }
    }
  }
  for (int i = tid; i < 2048; i += 256) cW0aTS[i] = W0aT[i];
  for (int i = tid; i < 512;  i += 256) cW1bS[i]  = W1b[i];
  __syncthreads();

  const int row = tid >> 2, p4 = tid & 3;

  // R1: v_tan0 = radial(v)  (in place)
  {
    f32x4 rv[4];
    float* vptr = &vlds[row*76 + p4*16];
    #pragma unroll
    for (int i = 0; i < 4; ++i) rv[i] = ((const f32x4*)vptr)[i];
    float ssq = 0.f;
    #pragma unroll
    for (int i = 0; i < 4; ++i)
      ssq += rv[i][0]*rv[i][0] + rv[i][1]*rv[i][1] + rv[i][2]*rv[i][2] + rv[i][3]*rv[i][3];
    ssq += __shfl_xor(ssq, 1); ssq += __shfl_xor(ssq, 2);
    const float fac = radial_factor(ssq, 1.0f, 1.0f);
    #pragma unroll
    for (int i = 0; i < 4; ++i){ rv[i] *= fac; ((f32x4*)vptr)[i] = rv[i]; }
  }
  __syncthreads();

  // R2: a0 = W0aE @ (2*vt0 - mb0) + b0a ; g0 = gelu(a0)
  {
    const int og = p4;
    float a0o[8];
    #pragma unroll
    for (int j = 0; j < 8; ++j) a0o[j] = cb0aS[og*8 + j];
    #pragma unroll 4
    for (int k = 0; k < 64; k += 4){
      f32x4 vtv = *(const f32x4*)&vlds[row*76 + k];
      f32x4 mm  = *(const f32x4*)&cmb0S[k];
      #pragma unroll
      for (int u = 0; u < 4; ++u){
        const float vc = 2.f*vtv[u] - mm[u];
        const f32x4* wp = (const f32x4*)&cW0aTS[(k+u)*32 + og*8];
        f32x4 w0 = wp[0], w1 = wp[1];
        #pragma unroll
        for (int j = 0; j < 4; ++j){ a0o[j] += w0[j]*vc; a0o[4+j] += w1[j]*vc; }
      }
    }
    #pragma unroll
    for (int j = 0; j < 8; ++j) gv[row*36 + og*8 + j] = gelu_f(a0o[j]);
  }
  __syncthreads();

  // R3: v1 = W0b@g0 + b0b; v_tan1, v_comb1
  {
    const int o1 = p4;
    float a1 = cb0bS[o1];
    #pragma unroll
    for (int k = 0; k < 32; k += 4){
      f32x4 gg = *(const f32x4*)&gv[row*36 + k];
      f32x4 ww = *(const f32x4*)&cW0bS[o1*32 + k];
      a1 += gg[0]*ww[0] + gg[1]*ww[1] + gg[2]*ww[2] + gg[3]*ww[3];
    }
    float ss1 = a1*a1;
    ss1 += __shfl_xor(ss1, 1); ss1 += __shfl_xor(ss1, 2);
    const float f1v = radial_factor(ss1, 0.8f, 0.8f);
    const float vt1 = a1*f1v;
    vlds[row*76 + 64 + o1] = vt1;
    vlds[row*76 + 68 + o1] = 2.f*vt1 - cmb1S[o1];
  }
  __syncthreads();

  // R4: a1 = W1aE @ vc1 + b1a ; g1 = gelu
  {
    const f32x4 vc1 = *(const f32x4*)&vlds[row*76 + 68];
    #pragma unroll
    for (int j = 0; j < 4; ++j){
      const int o = p4*4 + j;
      float s1 = cb1aS[o] + cW1aES[o*4+0]*vc1[0] + cW1aES[o*4+1]*vc1[1]
                          + cW1aES[o*4+2]*vc1[2] + cW1aES[o*4+3]*vc1[3];
      g1[row*20 + o] = gelu_f(s1);
    }
  }
  __syncthreads();

  // R5: v2 = W1b@g1 + b1b; v_tan2 -> gv
  {
    float v2[8]; float ss2 = 0.f;
    #pragma unroll
    for (int j = 0; j < 8; ++j){
      const int o = p4*8 + j;
      float s = cb1bS[o];
      #pragma unroll
      for (int k = 0; k < 16; k += 4){
        f32x4 gg = *(const f32x4*)&g1[row*20 + k];
        f32x4 ww = *(const f32x4*)&cW1bS[o*16 + k];
        s += gg[0]*ww[0] + gg[1]*ww[1] + gg[2]*ww[2] + gg[3]*ww[3];
      }
      v2[j] = s; ss2 += s*s;
    }
    ss2 += __shfl_xor(ss2, 1); ss2 += __shfl_xor(ss2, 2);
    const float f2v = radial_factor(ss2, 1.2f, 0.6f);
    #pragma unroll
    for (int j = 0; j < 8; ++j) gv[row*36 + p4*8 + j] = v2[j]*f2v;
  }
  __syncthreads();

  // R6: out = W_out @ concat(vt0, vt1, vt2) + b_out
  for (int idx = tid; idx < 640; idx += 256){
    const int r6 = idx/10, o = idx - r6*10;
    float s = cboutS[o];
    const float* wrow = &cWoutS[o*100];
    const float* vrow = &vlds[r6*76];
    #pragma unroll 4
    for (int k = 0; k < 68; k += 4){
      f32x4 a = *(const f32x4*)(vrow + k);
      f32x4 b = *(const f32x4*)(wrow + k);
      s += a[0]*b[0] + a[1]*b[1] + a[2]*b[2] + a[3]*b[3];
    }
    const float* v2row = &gv[r6*36];
    #pragma unroll 4
    for (int k = 0; k < 32; k += 4){
      f32x4 a = *(const f32x4*)(v2row + k);
      f32x4 b = *(const f32x4*)(wrow + 68 + k);
      s += a[0]*b[0] + a[1]*b[1] + a[2]*b[2] + a[3]*b[3];
    }
    out[(rowBase + (size_t)r6)*10 + o] = s;
  }
}

extern "C" void kernel_launch(void* const* d_in, const int* in_sizes, int n_in,
                              void* d_out, int out_size, void* d_ws, size_t ws_size,
                              hipStream_t stream)
{
  (void)n_in; (void)out_size; (void)ws_size;
  const float* x      = (const float*)d_in[0];
  const float* W_in   = (const float*)d_in[1];
  const float* b_in   = (const float*)d_in[2];
  const float* W_tan  = (const float*)d_in[3];
  const float* b_tan  = (const float*)d_in[4];
  const float* bp0    = (const float*)d_in[5];
  const float* bp1    = (const float*)d_in[6];
  /* bp2 = d_in[7] — dead in reference */
  const float* A_rot  = (const float*)d_in[8];
  const float* p_quat = (const float*)d_in[9];
  const float* q_quat = (const float*)d_in[10];
  const float* W0a    = (const float*)d_in[11];
  const float* b0a    = (const float*)d_in[12];
  const float* W0b    = (const float*)d_in[13];
  const float* b0b    = (const float*)d_in[14];
  const float* W1a    = (const float*)d_in[15];
  const float* b1a    = (const float*)d_in[16];
  const float* W1b    = (const float*)d_in[17];
  const float* b1b    = (const float*)d_in[18];
  const float* W_out  = (const float*)d_in[19];
  const float* b_out  = (const float*)d_in[20];

  char* ws = (char*)d_ws;
  unsigned short* Wcs = (unsigned short*)(ws + WS_WC);
  float* bcomb = (float*)(ws + WS_BCOMB);
  float* W0aE  = (float*)(ws + WS_W0AE);
  float* brot0 = (float*)(ws + WS_BROT0);
  float* bown0 = (float*)(ws + WS_BOWN0);
  float* W0aT  = (float*)(ws + WS_W0AT);
  float* mb0   = (float*)(ws + WS_MB0);
  float* mb1   = (float*)(ws + WS_MB1);
  float* W1aE  = (float*)(ws + WS_W1AE);
  float* zerog = (float*)(ws + WS_ZERO);

  const int Brows = in_sizes[0] / 784;
  const int nblk  = Brows / 64;

  prep_a<<<60, 256, 0, stream>>>(W_in, b_in, W_tan, b_tan, A_rot, W0a, bp0,
                                 Wcs, bcomb, W0aE, brot0, bown0);
  prep_small<<<1, 256, 0, stream>>>(bp1, p_quat, q_quat, b0a, W0b, b0b, W1a,
                                    W0aE, brot0, bown0, W0aT, mb0, mb1, W1aE, zerog);
  main_fused<<<nblk, 256, 0, stream>>>(x, Wcs, bcomb, W0aT, mb0, mb1, W1aE,
                                       b0a, W0b, b0b, b1a, W1b, b1b,
                                       W_out, b_out, zerog, (float*)d_out);
}